// Round 5
// baseline (590.108 us; speedup 1.0000x reference)
//
#include <hip/hip_runtime.h>

typedef unsigned short u16;
typedef unsigned int u32;

#define NN 8192
#define CAP 128
#define STRIPE 16

typedef __attribute__((ext_vector_type(8))) short short8;
typedef __attribute__((ext_vector_type(4))) float floatx4;

__device__ __forceinline__ u16 f2bf(float f) {
    union { float f; u32 i; } w;
    w.f = f;
    u32 i = w.i;
    u32 r = (i + 0x7FFFu + ((i >> 16) & 1u)) >> 16;
    return (u16)r;
}
__device__ __forceinline__ u32 pack2(float lo, float hi) {
    return (u32)f2bf(lo) | ((u32)f2bf(hi) << 16);
}
__device__ __forceinline__ float lo_bf(u32 v) {
    union { u32 i; float f; } w;
    w.i = v << 16;
    return w.f;
}
__device__ __forceinline__ float hi_bf(u32 v) {
    union { u32 i; float f; } w;
    w.i = v & 0xFFFF0000u;
    return w.f;
}
__device__ __forceinline__ float softplusf(float x) {
    return fmaxf(x, 0.0f) + log1pf(expf(-fabsf(x)));
}

#define GLOAD_LDS(gp, lp) __builtin_amdgcn_global_load_lds( \
    (const __attribute__((address_space(1))) u32*)(const void*)(gp), \
    (__attribute__((address_space(3))) u32*)(void*)(lp), 16, 0, 0)

// ---------------- PROLOGUE MEGA-KERNEL (unchanged, proven) ----------------
__global__ __launch_bounds__(256) void prologue(
    const float* __restrict__ adj,
    const float* __restrict__ emb, const float* __restrict__ pos,
    const float* __restrict__ W0, const float* __restrict__ W1,
    const float* __restrict__ W2, const float* __restrict__ W3,
    u16* __restrict__ T0, u16* __restrict__ T1,
    u16* __restrict__ T2, u16* __restrict__ T3,
    int* __restrict__ deg, float* __restrict__ snorm,
    u32* __restrict__ edges, u16* __restrict__ feat0)
{
    __shared__ char shraw[32 * 33 * 4];
    const int b = blockIdx.x;

    if (b < 2048) {
        int* cnt = (int*)shraw;
        const int wave = threadIdx.x >> 6, lane = threadIdx.x & 63;
        const int i = b * 4 + wave;
        if (threadIdx.x < 4) cnt[threadIdx.x] = 0;
        __syncthreads();
        const uint4* rowp = (const uint4*)(adj + (size_t)i * NN);
        u32* erow = edges + (size_t)i * CAP;
#pragma unroll 4
        for (int it = 0; it < 32; ++it) {
            uint4 v = rowp[it * 64 + lane];
            int jb = (it * 64 + lane) * 4;
            u32 w[4] = { v.x, v.y, v.z, v.w };
#pragma unroll
            for (int e = 0; e < 4; ++e) {
                int j = jb + e;
                if ((i != j) && ((w[e] & 0x7FFFFFFFu) != 0)) {
                    int slot = atomicAdd(&cnt[wave], 1);
                    if (slot < CAP) erow[slot] = (u32)j;
                }
            }
        }
        __syncthreads();
        int c = cnt[wave];
        float s = rsqrtf((float)max(c, 1));
        if (lane == 0) { deg[i] = c; snorm[i] = s; }
#pragma unroll
        for (int h = 0; h < 2; ++h) {
            int f = lane + h * 64;
            float v = (f < 125) ? emb[(size_t)i * 125 + f] : pos[(size_t)i * 3 + (f - 125)];
            feat0[(size_t)i * 128 + f] = f2bf(v * s);
        }
    } else {
        float (*tile)[33] = (float(*)[33])shraw;
        int b2 = b - 2048;
        int z = b2 >> 8, rem = b2 & 255;
        const float* W = (z == 0) ? W0 : (z == 1) ? W1 : (z == 2) ? W2 : W3;
        u16* WT       = (z == 0) ? T0 : (z == 1) ? T1 : (z == 2) ? T2 : T3;
        const int K = (z == 0) ? 128 : 512;
        const int N = 512;
        int bx = (rem & 15) * 32;
        int by = (rem >> 4) * 32;
        if (by >= K) return;
        int tx = threadIdx.x & 31, ty = threadIdx.x >> 5;
#pragma unroll
        for (int yy = ty; yy < 32; yy += 8)
            tile[yy][tx] = W[(size_t)(by + yy) * N + bx + tx];
        __syncthreads();
#pragma unroll
        for (int yy = ty; yy < 32; yy += 8)
            WT[(size_t)(bx + yy) * K + by + tx] = f2bf(tile[tx][yy]);
    }
}

// ---------------- FUSED SPMM + GEMM (one layer per launch) ----------------
// Block = one 16-row output stripe. Phase 1: gather-aggregate the stripe's
// rows from featIn (pre-scaled by snorm[src]), *snorm[dst], -> bf16 ->
// XOR-swizzled LDS A[16][Fin]. Phase 2: loop nb (8 x 64 output cols):
// stage WT tile [64n][128k] per kb via pre-swizzled-source global_load_lds,
// MFMA 16x16x32, epilogue bias+softplus (+snorm pre-scale for inner layers).
// No cross-block dependency: each block aggregates exactly its own rows.
// Grid 512 = 2 blocks/CU; LDS 16+16+8KB ~= 40KB; (256,2) -> VGPR cap 128.
__global__ __launch_bounds__(256, 2) void fused_spmm_gemm(
    const u32* __restrict__ edges, const int* __restrict__ deg,
    const float* __restrict__ snorm,
    const u16* __restrict__ featIn, const u16* __restrict__ WT,
    const float* __restrict__ bias,
    float* __restrict__ outf, u16* __restrict__ outb, int Fin)
{
    __shared__ __align__(16) u16 lA[STRIPE * 512];   // 16KB max (stride Fin*2 bytes)
    __shared__ __align__(16) u16 lB[64 * 128];       // 16KB  [64 n][128 k] swizzled slots
    __shared__ u32 se[STRIPE * CAP];                 // 8KB edge lists
    __shared__ float ssn[STRIPE];

    const int tid = threadIdx.x;
    const int wv = tid >> 6, ln = tid & 63;
    const int r0 = blockIdx.x * STRIPE;

    // ---- stage edge lists (full CAP; use bounded by deg) + snorm ----
    {
        const u32* src = edges + (size_t)r0 * CAP;
        for (int idx = tid; idx < STRIPE * CAP; idx += 256)
            se[idx] = src[idx];
        if (tid < STRIPE) ssn[tid] = snorm[r0 + tid];
    }
    __syncthreads();

    // ---- Phase 1: spmm into LDS A-stripe (wave wv owns rows wv*4..+4) ----
    if (Fin == 512) {
        const uint4* f4 = (const uint4*)featIn;
        for (int rr = 0; rr < 4; ++rr) {
            const int r = wv * 4 + rr;
            const int cnt = min(deg[r0 + r], CAP);
            const u32* ep = &se[r * CAP];
            float a[8] = {};
            int c = 0;
            for (; c + 8 <= cnt; c += 8) {       // 8-deep MLP: 8KB/wave in flight
                uint4 v[8];
#pragma unroll
                for (int u = 0; u < 8; ++u)
                    v[u] = f4[(size_t)ep[c + u] * 64 + ln];
#pragma unroll
                for (int u = 0; u < 8; ++u) {
                    a[0] += lo_bf(v[u].x); a[1] += hi_bf(v[u].x);
                    a[2] += lo_bf(v[u].y); a[3] += hi_bf(v[u].y);
                    a[4] += lo_bf(v[u].z); a[5] += hi_bf(v[u].z);
                    a[6] += lo_bf(v[u].w); a[7] += hi_bf(v[u].w);
                }
            }
            for (; c < cnt; ++c) {
                uint4 v = f4[(size_t)ep[c] * 64 + ln];
                a[0] += lo_bf(v.x); a[1] += hi_bf(v.x);
                a[2] += lo_bf(v.y); a[3] += hi_bf(v.y);
                a[4] += lo_bf(v.z); a[5] += hi_bf(v.z);
                a[6] += lo_bf(v.w); a[7] += hi_bf(v.w);
            }
            const float sj = ssn[r];
            uint4 o;
            o.x = pack2(a[0] * sj, a[1] * sj);
            o.y = pack2(a[2] * sj, a[3] * sj);
            o.z = pack2(a[4] * sj, a[5] * sj);
            o.w = pack2(a[6] * sj, a[7] * sj);
            // chunk ln (16B) -> slot ln ^ (r&7); row stride 1024B
            *(uint4*)((char*)lA + r * 1024 + ((ln * 16) ^ ((r & 7) << 4))) = o;
        }
    } else {   // Fin == 128
        const u32* f1 = (const u32*)featIn;
        for (int rr = 0; rr < 4; ++rr) {
            const int r = wv * 4 + rr;
            const int cnt = min(deg[r0 + r], CAP);
            const u32* ep = &se[r * CAP];
            float a0 = 0.f, a1 = 0.f;
            int c = 0;
            for (; c + 8 <= cnt; c += 8) {
                u32 v[8];
#pragma unroll
                for (int u = 0; u < 8; ++u)
                    v[u] = f1[(size_t)ep[c + u] * 64 + ln];
#pragma unroll
                for (int u = 0; u < 8; ++u) { a0 += lo_bf(v[u]); a1 += hi_bf(v[u]); }
            }
            for (; c < cnt; ++c) {
                u32 v = f1[(size_t)ep[c] * 64 + ln];
                a0 += lo_bf(v); a1 += hi_bf(v);
            }
            const float sj = ssn[r];
            // 4B at byte ln*4; XOR moves whole 16B chunk (lanes 4c..4c+3 together)
            *(u32*)((char*)lA + r * 256 + ((ln * 4) ^ ((r & 7) << 4))) = pack2(a0 * sj, a1 * sj);
        }
    }
    __syncthreads();

    // ---- Phase 2: GEMM  out[16 rows][512 cols] = softplus(A @ W + b) ----
    const int m16 = ln & 15, q = ln >> 4;
    const int sA = (m16 & 7) << 4;
    const int nK = Fin >> 7;                  // k0-blocks of 128
    const int rowBytesA = Fin * 2;
    // staging decomposition: thread t -> LDS byte t*16 + h*4096 = row(h*16+t>>4)*256 + (t&15)*16
    const int srn = tid >> 4;                 // staging row within 16-group
    const int ssl = tid & 15;                 // LDS slot
    const int nrow = wv * 16 + m16;           // this wave's B/n row (output col within nb)

    for (int nb = 0; nb < 8; ++nb) {
        floatx4 acc = {0.f, 0.f, 0.f, 0.f};
        for (int kb = 0; kb < nK; ++kb) {
            __syncthreads();                  // lB reuse guard
#pragma unroll
            for (int h = 0; h < 4; ++h) {
                const int row = h * 16 + srn;                    // n-row 0..63
                const int c = ssl ^ (row & 7);                   // pre-swizzled source chunk
                GLOAD_LDS(WT + (size_t)(nb * 64 + row) * Fin + kb * 128 + c * 8,
                          lB + tid * 8 + h * 2048);
            }
            __syncthreads();                  // drains vmcnt (barrier semantics)
#pragma unroll
            for (int kk = 0; kk < 4; ++kk) {
                short8 af = *(const short8*)((char*)lA + m16 * rowBytesA
                                + ((kb * 256 + kk * 64 + q * 16) ^ sA));
                short8 bf = *(const short8*)((char*)lB + nrow * 256
                                + (((kk * 4 + q) ^ (m16 & 7)) * 16));
                acc = __builtin_amdgcn_mfma_f32_16x16x32_bf16(af, bf, acc, 0, 0, 0);
            }
        }
        // epilogue: C/D layout col = lane&15, row = q*4 + reg  [m89/m91]
        const int col = nb * 64 + nrow;
        const float bvf = bias[col];
#pragma unroll
        for (int rr2 = 0; rr2 < 4; ++rr2) {
            const int r = q * 4 + rr2;
            const float v = softplusf(acc[rr2] + bvf);
            if (outf) outf[(size_t)(r0 + r) * 512 + col] = v;
            else      outb[(size_t)(r0 + r) * 512 + col] = f2bf(v * ssn[r]);
        }
    }
}

extern "C" void kernel_launch(void* const* d_in, const int* in_sizes, int n_in,
                              void* d_out, int out_size, void* d_ws, size_t ws_size,
                              hipStream_t stream)
{
    const float* atom_pos = (const float*)d_in[0];
    const float* dist_adj = (const float*)d_in[1];
    const float* atom_emb = (const float*)d_in[2];
    const float* Wm[4] = { (const float*)d_in[3], (const float*)d_in[5],
                           (const float*)d_in[7], (const float*)d_in[9] };
    const float* bv[4] = { (const float*)d_in[4], (const float*)d_in[6],
                           (const float*)d_in[8], (const float*)d_in[10] };

    char* p = (char*)d_ws;
    auto alloc = [&](size_t n) { char* r = p; p += (n + 255) & ~(size_t)255; return r; };
    int*   deg   = (int*)alloc(NN * 4);
    float* snorm = (float*)alloc(NN * 4);
    u32*   edges = (u32*)alloc((size_t)NN * CAP * 4);
    u16*   wt[4];
    wt[0] = (u16*)alloc(512 * 128 * 2);
    wt[1] = (u16*)alloc(512 * 512 * 2);
    wt[2] = (u16*)alloc(512 * 512 * 2);
    wt[3] = (u16*)alloc(512 * 512 * 2);
    u16* buf0 = (u16*)alloc((size_t)NN * 512 * 2);   // layer0 input (128-wide) / ping-pong
    u16* buf1 = (u16*)alloc((size_t)NN * 512 * 2);

    prologue<<<2048 + 1024, 256, 0, stream>>>(
        dist_adj, atom_emb, atom_pos,
        Wm[0], Wm[1], Wm[2], Wm[3], wt[0], wt[1], wt[2], wt[3],
        deg, snorm, edges, buf0);

    // ping-pong: gather reads whole in-buffer, so out-buffer must differ
    const u16* fin = buf0;
    u16* fout = buf1;
    int F = 128;
    for (int l = 0; l < 4; ++l) {
        float* of = (l == 3) ? (float*)d_out : nullptr;
        u16*   ob = (l == 3) ? nullptr : fout;
        fused_spmm_gemm<<<NN / STRIPE, 256, 0, stream>>>(
            edges, deg, snorm, fin, wt[l], bv[l], of, ob, F);
        const u16* t = fin; fin = fout; fout = (u16*)t;
        F = 512;
    }
}

// Round 6
// 547.321 us; speedup vs baseline: 1.0782x; 1.0782x over previous
//
#include <hip/hip_runtime.h>

typedef unsigned short u16;
typedef unsigned int u32;

#define NN 8192
#define CAP 128

typedef __attribute__((ext_vector_type(8))) short short8;
typedef __attribute__((ext_vector_type(4))) float floatx4;

__device__ __forceinline__ u16 f2bf(float f) {
    union { float f; u32 i; } w;
    w.f = f;
    u32 i = w.i;
    u32 r = (i + 0x7FFFu + ((i >> 16) & 1u)) >> 16;
    return (u16)r;
}
__device__ __forceinline__ float lo_bf(u32 v) {
    union { u32 i; float f; } w;
    w.i = v << 16;
    return w.f;
}
__device__ __forceinline__ float hi_bf(u32 v) {
    union { u32 i; float f; } w;
    w.i = v & 0xFFFF0000u;
    return w.f;
}
__device__ __forceinline__ float softplusf(float x) {
    return fmaxf(x, 0.0f) + log1pf(expf(-fabsf(x)));
}

// ---------------- PROLOGUE MEGA-KERNEL (R0-exact, proven) ----------------
__global__ __launch_bounds__(256) void prologue(
    const float* __restrict__ adj,
    const float* __restrict__ emb, const float* __restrict__ pos,
    const float* __restrict__ W0, const float* __restrict__ W1,
    const float* __restrict__ W2, const float* __restrict__ W3,
    u16* __restrict__ T0, u16* __restrict__ T1,
    u16* __restrict__ T2, u16* __restrict__ T3,
    int* __restrict__ deg, float* __restrict__ snorm,
    u32* __restrict__ edges, u16* __restrict__ feat0)
{
    __shared__ char shraw[32 * 33 * 4];   // union: cnt[4] (build) | tile[32][33] (transpose)
    const int b = blockIdx.x;

    if (b < 2048) {
        int* cnt = (int*)shraw;
        const int wave = threadIdx.x >> 6, lane = threadIdx.x & 63;
        const int i = b * 4 + wave;
        if (threadIdx.x < 4) cnt[threadIdx.x] = 0;
        __syncthreads();
        const uint4* rowp = (const uint4*)(adj + (size_t)i * NN);
        u32* erow = edges + (size_t)i * CAP;
#pragma unroll 4
        for (int it = 0; it < 32; ++it) {            // 32 * 64 lanes * 4 f32 = 8192
            uint4 v = rowp[it * 64 + lane];
            int jb = (it * 64 + lane) * 4;
            u32 w[4] = { v.x, v.y, v.z, v.w };
#pragma unroll
            for (int e = 0; e < 4; ++e) {
                int j = jb + e;
                if ((i != j) && ((w[e] & 0x7FFFFFFFu) != 0)) {
                    int slot = atomicAdd(&cnt[wave], 1);   // LDS atomic, wave-local
                    if (slot < CAP) erow[slot] = (u32)j;
                }
            }
        }
        __syncthreads();
        int c = cnt[wave];
        float s = rsqrtf((float)max(c, 1));
        if (lane == 0) { deg[i] = c; snorm[i] = s; }
#pragma unroll
        for (int h = 0; h < 2; ++h) {
            int f = lane + h * 64;
            float v = (f < 125) ? emb[(size_t)i * 125 + f] : pos[(size_t)i * 3 + (f - 125)];
            feat0[(size_t)i * 128 + f] = f2bf(v * s);
        }
    } else {
        float (*tile)[33] = (float(*)[33])shraw;
        int b2 = b - 2048;
        int z = b2 >> 8, rem = b2 & 255;
        const float* W = (z == 0) ? W0 : (z == 1) ? W1 : (z == 2) ? W2 : W3;
        u16* WT       = (z == 0) ? T0 : (z == 1) ? T1 : (z == 2) ? T2 : T3;
        const int K = (z == 0) ? 128 : 512;
        const int N = 512;
        int bx = (rem & 15) * 32;   // n
        int by = (rem >> 4) * 32;   // k
        if (by >= K) return;        // block-uniform
        int tx = threadIdx.x & 31, ty = threadIdx.x >> 5;
#pragma unroll
        for (int yy = ty; yy < 32; yy += 8)
            tile[yy][tx] = W[(size_t)(by + yy) * N + bx + tx];
        __syncthreads();
#pragma unroll
        for (int yy = ty; yy < 32; yy += 8)
            WT[(size_t)(bx + yy) * K + by + tx] = f2bf(tile[tx][yy]);
    }
}

// ---------------- SpMM F=512: out[j,:] = snorm[j] * sum_{i in N(j)} featS[i,:] ----------------
// R6: 8-deep explicit load batching (validated numerically in R5's fused phase-1).
// Doubles memory-level parallelism vs unroll-4; accumulation order preserved
// (u ascending == c ascending) -> bit-identical output.
__global__ __launch_bounds__(256) void spmm512(
    const u32* __restrict__ edges, const int* __restrict__ deg,
    const float* __restrict__ snorm,
    const uint4* __restrict__ feat4, uint4* __restrict__ out4)
{
    __shared__ int sh_i[4][CAP];
    const int wave = threadIdx.x >> 6, lane = threadIdx.x & 63;
    const int j = blockIdx.x * 4 + wave;
    const int cnt = min(deg[j], CAP);
    for (int c = lane; c < cnt; c += 64)
        sh_i[wave][c] = (int)edges[(size_t)j * CAP + c];
    __syncthreads();
    float a[8] = {};
    int c = 0;
    for (; c + 8 <= cnt; c += 8) {           // 8 x 16B/lane in flight (8KB/wave)
        uint4 v[8];
#pragma unroll
        for (int u = 0; u < 8; ++u)
            v[u] = feat4[(size_t)sh_i[wave][c + u] * 64 + lane];
#pragma unroll
        for (int u = 0; u < 8; ++u) {
            a[0] += lo_bf(v[u].x); a[1] += hi_bf(v[u].x);
            a[2] += lo_bf(v[u].y); a[3] += hi_bf(v[u].y);
            a[4] += lo_bf(v[u].z); a[5] += hi_bf(v[u].z);
            a[6] += lo_bf(v[u].w); a[7] += hi_bf(v[u].w);
        }
    }
    for (; c < cnt; ++c) {
        uint4 v = feat4[(size_t)sh_i[wave][c] * 64 + lane];
        a[0] += lo_bf(v.x); a[1] += hi_bf(v.x);
        a[2] += lo_bf(v.y); a[3] += hi_bf(v.y);
        a[4] += lo_bf(v.z); a[5] += hi_bf(v.z);
        a[6] += lo_bf(v.w); a[7] += hi_bf(v.w);
    }
    float sj = snorm[j];
    uint4 o;
    o.x = (u32)f2bf(a[0] * sj) | ((u32)f2bf(a[1] * sj) << 16);
    o.y = (u32)f2bf(a[2] * sj) | ((u32)f2bf(a[3] * sj) << 16);
    o.z = (u32)f2bf(a[4] * sj) | ((u32)f2bf(a[5] * sj) << 16);
    o.w = (u32)f2bf(a[6] * sj) | ((u32)f2bf(a[7] * sj) << 16);
    out4[(size_t)j * 64 + lane] = o;
}

// ---------------- SpMM F=128 (layer 0): 8-deep batched u32 loads ----------------
__global__ __launch_bounds__(256) void spmm128(
    const u32* __restrict__ edges, const int* __restrict__ deg,
    const float* __restrict__ snorm,
    const u32* __restrict__ feat1, u32* __restrict__ out1)
{
    __shared__ int sh_i[4][CAP];
    const int wave = threadIdx.x >> 6, lane = threadIdx.x & 63;
    const int j = blockIdx.x * 4 + wave;
    const int cnt = min(deg[j], CAP);
    for (int c = lane; c < cnt; c += 64)
        sh_i[wave][c] = (int)edges[(size_t)j * CAP + c];
    __syncthreads();
    float a0 = 0.f, a1 = 0.f;
    int c = 0;
    for (; c + 8 <= cnt; c += 8) {
        u32 v[8];
#pragma unroll
        for (int u = 0; u < 8; ++u)
            v[u] = feat1[(size_t)sh_i[wave][c + u] * 64 + lane];
#pragma unroll
        for (int u = 0; u < 8; ++u) { a0 += lo_bf(v[u]); a1 += hi_bf(v[u]); }
    }
    for (; c < cnt; ++c) {
        u32 v = feat1[(size_t)sh_i[wave][c] * 64 + lane];
        a0 += lo_bf(v); a1 += hi_bf(v);
    }
    float sj = snorm[j];
    out1[(size_t)j * 64 + lane] = (u32)f2bf(a0 * sj) | ((u32)f2bf(a1 * sj) << 16);
}

// ---------------- GEMM (R0-exact, proven): out = softplus(A[M,K] @ W + b) ----------------
// BM=64, BN=64, BK=64 -> 1024 blocks = 4/CU; XOR-swizzled LDS (conflict-free);
// async global_load_lds staging.
__global__ __launch_bounds__(256, 4) void gemm_bias_softplus(
    const u16* __restrict__ A, const u16* __restrict__ BT,
    const float* __restrict__ bias, const float* __restrict__ snorm,
    float* __restrict__ outf, u16* __restrict__ outb,
    int M, int N, int K)
{
    __shared__ u16 lA[64 * 64];    // [row][k] 8KB, swizzled slots
    __shared__ u16 lB[64 * 64];    // [col][k] 8KB, swizzled slots
    const int tid = threadIdx.x;
    const int wave = tid >> 6;
    const int lane = tid & 63;
    const int q = lane >> 4;
    const int m16 = lane & 15;
    const int wm = (wave >> 1) * 32;
    const int wn = (wave & 1) * 32;
    const int bm = blockIdx.x, bn = blockIdx.y;

    const int r32 = tid >> 3;             // 0..31 staging row within half
    const int cb  = tid & 7;              // LDS slot index 0..7
    const int cg  = cb ^ (r32 & 7);       // swizzled global col block
    const u16* gA0 = A  + (size_t)(bm * 64 + r32) * K + cg * 8;
    const u16* gA1 = A  + (size_t)(bm * 64 + 32 + r32) * K + cg * 8;
    const u16* gB0 = BT + (size_t)(bn * 64 + r32) * K + cg * 8;
    const u16* gB1 = BT + (size_t)(bn * 64 + 32 + r32) * K + cg * 8;
    u16* lAp0 = lA + tid * 8;
    u16* lAp1 = lA + 2048 + tid * 8;
    u16* lBp0 = lB + tid * 8;
    u16* lBp1 = lB + 2048 + tid * 8;

    floatx4 acc[2][2] = {};

    for (int k0 = 0; k0 < K; k0 += 64) {
        __builtin_amdgcn_global_load_lds(
            (const __attribute__((address_space(1))) u32*)(const void*)(gA0 + k0),
            (__attribute__((address_space(3))) u32*)(void*)lAp0, 16, 0, 0);
        __builtin_amdgcn_global_load_lds(
            (const __attribute__((address_space(1))) u32*)(const void*)(gA1 + k0),
            (__attribute__((address_space(3))) u32*)(void*)lAp1, 16, 0, 0);
        __builtin_amdgcn_global_load_lds(
            (const __attribute__((address_space(1))) u32*)(const void*)(gB0 + k0),
            (__attribute__((address_space(3))) u32*)(void*)lBp0, 16, 0, 0);
        __builtin_amdgcn_global_load_lds(
            (const __attribute__((address_space(1))) u32*)(const void*)(gB1 + k0),
            (__attribute__((address_space(3))) u32*)(void*)lBp1, 16, 0, 0);
        __syncthreads();   // barrier semantics drain vmcnt first

        short8 af[2][2], bfr[2][2];
#pragma unroll
        for (int im = 0; im < 2; ++im) {
            int row = wm + im * 16 + m16;
#pragma unroll
            for (int kk = 0; kk < 2; ++kk) {
                int slot = (kk * 4 + q) ^ (m16 & 7);
                af[im][kk] = *(const short8*)&lA[row * 64 + slot * 8];
            }
        }
#pragma unroll
        for (int in = 0; in < 2; ++in) {
            int row = wn + in * 16 + m16;
#pragma unroll
            for (int kk = 0; kk < 2; ++kk) {
                int slot = (kk * 4 + q) ^ (m16 & 7);
                bfr[in][kk] = *(const short8*)&lB[row * 64 + slot * 8];
            }
        }
#pragma unroll
        for (int kk = 0; kk < 2; ++kk)
#pragma unroll
            for (int im = 0; im < 2; ++im)
#pragma unroll
                for (int in = 0; in < 2; ++in)
                    acc[im][in] = __builtin_amdgcn_mfma_f32_16x16x32_bf16(
                        af[im][kk], bfr[in][kk], acc[im][in], 0, 0, 0);
        __syncthreads();
    }

    // epilogue: C/D layout col = lane&15, row = q*4 + reg  [measured m89/m91]
#pragma unroll
    for (int im = 0; im < 2; ++im) {
#pragma unroll
        for (int in = 0; in < 2; ++in) {
            int col = bn * 64 + wn + in * 16 + m16;
            float bvf = bias[col];
#pragma unroll
            for (int r = 0; r < 4; ++r) {
                int row = bm * 64 + wm + im * 16 + q * 4 + r;
                float v = softplusf(acc[im][in][r] + bvf);
                if (outf) outf[(size_t)row * N + col] = v;
                else      outb[(size_t)row * N + col] = f2bf(v * snorm[row]);
            }
        }
    }
}

extern "C" void kernel_launch(void* const* d_in, const int* in_sizes, int n_in,
                              void* d_out, int out_size, void* d_ws, size_t ws_size,
                              hipStream_t stream)
{
    const float* atom_pos = (const float*)d_in[0];
    const float* dist_adj = (const float*)d_in[1];
    const float* atom_emb = (const float*)d_in[2];
    const float* Wm[4] = { (const float*)d_in[3], (const float*)d_in[5],
                           (const float*)d_in[7], (const float*)d_in[9] };
    const float* bv[4] = { (const float*)d_in[4], (const float*)d_in[6],
                           (const float*)d_in[8], (const float*)d_in[10] };

    char* p = (char*)d_ws;
    auto alloc = [&](size_t n) { char* r = p; p += (n + 255) & ~(size_t)255; return r; };
    int*   deg   = (int*)alloc(NN * 4);
    float* snorm = (float*)alloc(NN * 4);
    u32*   edges = (u32*)alloc((size_t)NN * CAP * 4);
    u16*   wt[4];
    wt[0] = (u16*)alloc(512 * 128 * 2);
    wt[1] = (u16*)alloc(512 * 512 * 2);
    wt[2] = (u16*)alloc(512 * 512 * 2);
    wt[3] = (u16*)alloc(512 * 512 * 2);
    u16* buf0 = (u16*)alloc((size_t)NN * 512 * 2);
    u16* buf1 = (u16*)alloc((size_t)NN * 512 * 2);

    prologue<<<2048 + 1024, 256, 0, stream>>>(
        dist_adj, atom_emb, atom_pos,
        Wm[0], Wm[1], Wm[2], Wm[3], wt[0], wt[1], wt[2], wt[3],
        deg, snorm, edges, buf0);

    const u16* feat = buf0;
    int F = 128;
    for (int l = 0; l < 4; ++l) {
        if (F == 128)
            spmm128<<<NN / 4, 256, 0, stream>>>(edges, deg, snorm,
                                                (const u32*)feat, (u32*)buf1);
        else
            spmm512<<<NN / 4, 256, 0, stream>>>(edges, deg, snorm,
                                                (const uint4*)feat, (uint4*)buf1);
        float* outf = (l == 3) ? (float*)d_out : nullptr;
        u16*   outb = (l == 3) ? nullptr : buf0;
        gemm_bias_softplus<<<dim3(NN / 64, 512 / 64), 256, 0, stream>>>(
            buf1, wt[l], bv[l], snorm, outf, outb, NN, 512, F);
        feat = buf0;
        F = 512;
    }
}